// Round 2
// 552.515 us; speedup vs baseline: 1.0434x; 1.0434x over previous
//
#include <hip/hip_runtime.h>
#include <hip/hip_bf16.h>
#include <cstdint>
#include <cstddef>

// Problem constants
#define B_SZ   16
#define S_LEN  2048
#define H_DIM  768
#define M_ROWS (B_SZ * (S_LEN - 1))   // 32752 GEMM rows

typedef __attribute__((ext_vector_type(8))) __bf16 bf16x8;
typedef __attribute__((ext_vector_type(8))) unsigned short ushort8;
typedef __attribute__((ext_vector_type(4))) float floatx4;

__device__ __forceinline__ float bf2f(unsigned short h) {
  union { unsigned u; float f; } v; v.u = ((unsigned)h) << 16; return v.f;
}
__device__ __forceinline__ unsigned short f2bf(float f) {
  union { float f; unsigned u; } v; v.f = f;
  unsigned u = v.u + 0x7fffu + ((v.u >> 16) & 1u);  // RNE
  return (unsigned short)(u >> 16);
}

// async global->LDS, 16B per lane. LDS dest = wave-uniform base + lane*16.
__device__ __forceinline__ void load_lds16(const void* g, void* l) {
  __builtin_amdgcn_global_load_lds(
      (const __attribute__((address_space(1))) void*)g,
      (__attribute__((address_space(3))) void*)l, 16, 0, 0);
}

// ---------------------------------------------------------------------------
// Kernel 0: convert the 5 small fp32 tensors (E_d, E_c, W_cd, W_hid, W_cdh)
// to bf16 in workspace. Segment bounds are compile-time constants.
// ---------------------------------------------------------------------------
#define N_ED   (512 * 128)        // 65536
#define N_EC   (512 * 128)        // 65536
#define N_WCD  (128 * 256)        // 32768
#define N_WHID (768 * 1536)       // 1179648
#define N_WCDH (768 * 896)        // 688128
#define N_CONV (N_ED + N_EC + N_WCD + N_WHID + N_WCDH)   // 2031616 (= 992*256*8)

__global__ void convert_weights_kernel(const float* __restrict__ Ed,
                                       const float* __restrict__ Ec,
                                       const float* __restrict__ Wcd,
                                       const float* __restrict__ Whid,
                                       const float* __restrict__ Wcdh,
                                       unsigned short* __restrict__ ed_b,
                                       unsigned short* __restrict__ ec_b,
                                       unsigned short* __restrict__ wcd_b,
                                       unsigned short* __restrict__ whid_b,
                                       unsigned short* __restrict__ wcdh_b) {
  long i = ((long)blockIdx.x * blockDim.x + threadIdx.x) * 8;
  const float* s; unsigned short* dst; long off;
  if (i < N_ED)                            { s = Ed;   dst = ed_b;   off = i; }
  else if (i < N_ED + N_EC)                { s = Ec;   dst = ec_b;   off = i - N_ED; }
  else if (i < N_ED + N_EC + N_WCD)        { s = Wcd;  dst = wcd_b;  off = i - (N_ED + N_EC); }
  else if (i < N_ED + N_EC + N_WCD + N_WHID) { s = Whid; dst = whid_b; off = i - (N_ED + N_EC + N_WCD); }
  else                                     { s = Wcdh; dst = wcdh_b; off = i - (N_ED + N_EC + N_WCD + N_WHID); }
  floatx4 v0 = *(const floatx4*)(s + off);
  floatx4 v1 = *(const floatx4*)(s + off + 4);
  ushort8 o;
#pragma unroll
  for (int t = 0; t < 4; ++t) { o[t] = f2bf(v0[t]); o[t + 4] = f2bf(v1[t]); }
  *(ushort8*)(dst + off) = o;
}

// ---------------------------------------------------------------------------
// Kernel 1: seqs_u = seqs + E_u[u]  -> d_out (fp32) and ws bf16 copy
// ---------------------------------------------------------------------------
__global__ void embed_add_kernel(const float* __restrict__ seqs,
                                 const int* __restrict__ u,
                                 const float* __restrict__ Eu,
                                 float* __restrict__ out,
                                 unsigned short* __restrict__ sub, int nchunks) {
  int c = blockIdx.x * blockDim.x + threadIdx.x;
  if (c >= nchunks) return;
  int row = c / 96;            // 96 chunks of 8 per 768-row
  int hc  = c - row * 96;
  int uid = u[row];
  const floatx4* sp = (const floatx4*)seqs + (size_t)c * 2;
  const floatx4* ep = (const floatx4*)(Eu + (size_t)uid * H_DIM + hc * 8);
  floatx4 a0 = sp[0], a1 = sp[1];
  floatx4 b0 = ep[0], b1 = ep[1];
  floatx4 r0, r1; ushort8 ob;
#pragma unroll
  for (int t = 0; t < 4; ++t) {
    r0[t] = a0[t] + b0[t];
    r1[t] = a1[t] + b1[t];
    ob[t] = f2bf(r0[t]); ob[t + 4] = f2bf(r1[t]);
  }
  floatx4* op = (floatx4*)out + (size_t)c * 2;
  op[0] = r0; op[1] = r1;
  *((ushort8*)sub + c) = ob;
}

// ---------------------------------------------------------------------------
// Fused NT GEMM with relu:  out[n, o] = relu(sum_k A[n,k] * W[o,k])  (all bf16)
// MODE 0: A = cat(E_d[d[n]], E_c[c[n]])          K=256,  NOUT=128
// MODE 1: A = cat(seqs_u[n], seqs_u[n+1]) pairs  K=1536, NOUT=768
// MODE 2: A = cat(ph[n], d_c[n])                 K=896,  NOUT=768
// 128x128 block tile, 4 waves (2x2), each wave 4x4 MFMA 16x16x32 frags.
//
// This round:
//  * T1: bijective XCD-chunked remap of blockIdx (m204) so the NT blocks
//    sharing one A-tile run on the SAME XCD's L2 -> A fetched once from HBM.
//  * T2 (rule 21, both-sides-or-neither): LDS dest stays linear for
//    global_load_lds; the GLOBAL source 16B-chunk is pre-swizzled
//    (cc ^ lrow) and the ds_read applies the same XOR (chunk ^ (row&7)).
//    Spreads each 16-lane column read over all 8 row slots -> b128 floor.
// ---------------------------------------------------------------------------
template <int MODE, int K, int LDW, int NOUT>
__global__ __launch_bounds__(256)
void gemm_nt_relu(const unsigned short* __restrict__ A0,
                  const unsigned short* __restrict__ A1,
                  const int* __restrict__ idx0,
                  const int* __restrict__ idx1,
                  const unsigned short* __restrict__ W,
                  unsigned short* __restrict__ out) {
  constexpr int NT = NOUT / 128;

  // --- T1: bijective XCD chunking (nwg % 8 handled per m204) ---
  const int nwg = gridDim.x;
  const int q = nwg >> 3, r = nwg & 7;
  const int xcd = blockIdx.x & 7, lid = blockIdx.x >> 3;
  const int wgid = (xcd < r ? xcd * (q + 1) : r * (q + 1) + (xcd - r) * q) + lid;
  const int bm = wgid / NT;
  const int bn = wgid - bm * NT;

  __shared__ unsigned short As[128 * 64];
  __shared__ unsigned short Ws[128 * 64];

  const int tid  = threadIdx.x;
  const int lane = tid & 63;
  const int wave = tid >> 6;
  const int lrow = lane >> 3;   // 0..7  (== staged LDS row & 7)
  const int cc   = lane & 7;    // 16B chunk slot within 64-col row (LDS side)
  const int scc  = cc ^ lrow;   // pre-swizzled GLOBAL chunk for this slot
  const int wm   = wave >> 1, wn = wave & 1;
  const int m16  = lane & 15, quad = lane >> 4;
  const int rxor = m16 & 7;     // read-side XOR (row & 7)

  floatx4 acc[4][4] = {};

  for (int kt = 0; kt < K / 64; ++kt) {
    const int colbase = kt * 64;
    // ---- stage A[128][64] and W[128][64] tiles (16B/lane async) ----
#pragma unroll
    for (int it = 0; it < 4; ++it) {
      int row = it * 32 + wave * 8 + lrow;
      int n = bm * 128 + row;
      if (n >= M_ROWS) n = M_ROWS - 1;   // clamp: read valid, store masked later
      const unsigned short* g;
      if constexpr (MODE == 0) {
        if (colbase < 128) g = A0 + (size_t)idx0[n] * 128 + colbase + scc * 8;
        else               g = A1 + (size_t)idx1[n] * 128 + (colbase - 128) + scc * 8;
      } else if constexpr (MODE == 1) {
        int b = n / (S_LEN - 1);
        int s = n - b * (S_LEN - 1);
        int grow = b * S_LEN + s + (colbase >= H_DIM ? 1 : 0);
        int gcol = (colbase >= H_DIM ? colbase - H_DIM : colbase) + scc * 8;
        g = A0 + (size_t)grow * H_DIM + gcol;
      } else {
        if (colbase < H_DIM) g = A0 + (size_t)n * H_DIM + colbase + scc * 8;
        else                 g = A1 + (size_t)n * 128 + (colbase - H_DIM) + scc * 8;
      }
      load_lds16(g, &As[(it * 256 + wave * 64) * 8]);

      int wrow = bn * 128 + row;
      const unsigned short* gw = W + (size_t)wrow * LDW + colbase + scc * 8;
      load_lds16(gw, &Ws[(it * 256 + wave * 64) * 8]);
    }
    __syncthreads();

    // ---- MFMA on the 64-deep K tile (swizzled ds_read) ----
#pragma unroll
    for (int kk = 0; kk < 64; kk += 32) {
      const int k8 = kk >> 3;     // 0 or 4
      bf16x8 a[4], b[4];
#pragma unroll
      for (int i = 0; i < 4; ++i) {
        int rr = wm * 64 + i * 16 + m16;
        a[i] = *(const bf16x8*)&As[rr * 64 + (((k8 + quad) ^ rxor) << 3)];
      }
#pragma unroll
      for (int j = 0; j < 4; ++j) {
        int rr = wn * 64 + j * 16 + m16;
        b[j] = *(const bf16x8*)&Ws[rr * 64 + (((k8 + quad) ^ rxor) << 3)];
      }
#pragma unroll
      for (int i = 0; i < 4; ++i)
#pragma unroll
        for (int j = 0; j < 4; ++j)
          acc[i][j] = __builtin_amdgcn_mfma_f32_16x16x32_bf16(a[i], b[j], acc[i][j], 0, 0, 0);
    }
    __syncthreads();
  }

  // ---- epilogue: relu + bf16 store. C/D: col=lane&15, row=quad*4+reg ----
#pragma unroll
  for (int i = 0; i < 4; ++i) {
#pragma unroll
    for (int r2 = 0; r2 < 4; ++r2) {
      int row = bm * 128 + wm * 64 + i * 16 + quad * 4 + r2;
      if (row < M_ROWS) {
#pragma unroll
        for (int j = 0; j < 4; ++j) {
          int col = bn * 128 + wn * 64 + j * 16 + m16;
          out[(size_t)row * NOUT + col] = f2bf(fmaxf(acc[i][j][r2], 0.0f));
        }
      }
    }
  }
}

// ---------------------------------------------------------------------------
// Kernel 5: out[b,s] += m[b,s]*(s<S-1) + m[b,s-1]*(s>=2)   (out fp32, m bf16)
// ---------------------------------------------------------------------------
__global__ void final_add_kernel(const unsigned short* __restrict__ mm,
                                 float* __restrict__ out, int nchunks) {
  int c = blockIdx.x * blockDim.x + threadIdx.x;
  if (c >= nchunks) return;
  int row = c / 96;
  int hc  = c - row * 96;
  int b = row >> 11;            // S_LEN = 2048
  int s = row & (S_LEN - 1);
  floatx4* op = (floatx4*)out + (size_t)c * 2;
  floatx4 v0 = op[0], v1 = op[1];
  int mrow = b * (S_LEN - 1) + s;
  if (s < S_LEN - 1) {
    ushort8 x = *(const ushort8*)(mm + (size_t)mrow * H_DIM + hc * 8);
#pragma unroll
    for (int t = 0; t < 4; ++t) { v0[t] += bf2f(x[t]); v1[t] += bf2f(x[t + 4]); }
  }
  if (s >= 2) {
    ushort8 x = *(const ushort8*)(mm + (size_t)(mrow - 1) * H_DIM + hc * 8);
#pragma unroll
    for (int t = 0; t < 4; ++t) { v0[t] += bf2f(x[t]); v1[t] += bf2f(x[t + 4]); }
  }
  op[0] = v0; op[1] = v1;
}

// ---------------------------------------------------------------------------
extern "C" void kernel_launch(void* const* d_in, const int* in_sizes, int n_in,
                              void* d_out, int out_size, void* d_ws, size_t ws_size,
                              hipStream_t stream) {
  const float* seqs  = (const float*)d_in[0];
  const int*   d_idx = (const int*)d_in[1];
  const int*   c_idx = (const int*)d_in[2];
  const int*   u_idx = (const int*)d_in[3];
  const float* E_d   = (const float*)d_in[4];
  const float* E_c   = (const float*)d_in[5];
  const float* E_u   = (const float*)d_in[6];
  const float* W_cd  = (const float*)d_in[7];
  const float* W_hid = (const float*)d_in[8];
  const float* W_cdh = (const float*)d_in[9];
  float* out = (float*)d_out;

  // bf16 workspace layout (ushort units); all segment sizes are multiples of 8
  unsigned short* sub   = (unsigned short*)d_ws;                 // seqs_u bf16 [16*2048, 768]
  unsigned short* ph    = sub   + (size_t)B_SZ * S_LEN * H_DIM;  // [32752, 768]
  unsigned short* mmb   = ph    + (size_t)M_ROWS * H_DIM;        // [32752, 768]
  unsigned short* dc    = mmb   + (size_t)M_ROWS * H_DIM;        // [32752, 128]
  unsigned short* ed_b  = dc    + (size_t)M_ROWS * 128;
  unsigned short* ec_b  = ed_b  + N_ED;
  unsigned short* wcd_b = ec_b  + N_EC;
  unsigned short* whid_b = wcd_b + N_WCD;
  unsigned short* wcdh_b = whid_b + N_WHID;

  const int nchunks = B_SZ * S_LEN * (H_DIM / 8);   // 3,145,728
  const int mtiles = (M_ROWS + 127) / 128;          // 256

  // 0) fp32 -> bf16 conversions of embeddings + weights
  convert_weights_kernel<<<N_CONV / (256 * 8), 256, 0, stream>>>(
      E_d, E_c, W_cd, W_hid, W_cdh, ed_b, ec_b, wcd_b, whid_b, wcdh_b);
  // 1) seqs_u = seqs + E_u[u]  -> out (fp32) + sub (bf16)
  embed_add_kernel<<<(nchunks + 255) / 256, 256, 0, stream>>>(seqs, u_idx, E_u, out, sub, nchunks);
  // 2) d_c = relu(cat(E_d[d], E_c[c]) @ W_cd^T)
  gemm_nt_relu<0, 256, 256, 128><<<mtiles * 1, 256, 0, stream>>>(ed_b, ec_b, d_idx, c_idx, wcd_b, dc);
  // 3) ph = relu(pairs(seqs_u) @ W_hid^T)
  gemm_nt_relu<1, 1536, 1536, 768><<<mtiles * 6, 256, 0, stream>>>(sub, nullptr, nullptr, nullptr, whid_b, ph);
  // 4) m = relu(cat(ph, d_c) @ W_cdh^T)
  gemm_nt_relu<2, 896, 896, 768><<<mtiles * 6, 256, 0, stream>>>(ph, dc, nullptr, nullptr, wcdh_b, mmb);
  // 5) out += shifted m
  final_add_kernel<<<(nchunks + 255) / 256, 256, 0, stream>>>(mmb, out, nchunks);
}

// Round 3
// 549.251 us; speedup vs baseline: 1.0497x; 1.0059x over previous
//
#include <hip/hip_runtime.h>
#include <hip/hip_bf16.h>
#include <cstdint>
#include <cstddef>

// Problem constants
#define B_SZ   16
#define S_LEN  2048
#define H_DIM  768
#define M_ROWS (B_SZ * (S_LEN - 1))   // 32752 GEMM rows

typedef __attribute__((ext_vector_type(8))) __bf16 bf16x8;
typedef __attribute__((ext_vector_type(8))) unsigned short ushort8;
typedef __attribute__((ext_vector_type(4))) float floatx4;

__device__ __forceinline__ float bf2f(unsigned short h) {
  union { unsigned u; float f; } v; v.u = ((unsigned)h) << 16; return v.f;
}
__device__ __forceinline__ unsigned short f2bf(float f) {
  union { float f; unsigned u; } v; v.f = f;
  unsigned u = v.u + 0x7fffu + ((v.u >> 16) & 1u);  // RNE
  return (unsigned short)(u >> 16);
}

// async global->LDS, 16B per lane. LDS dest = wave-uniform base + lane*16.
__device__ __forceinline__ void load_lds16(const void* g, void* l) {
  __builtin_amdgcn_global_load_lds(
      (const __attribute__((address_space(1))) void*)g,
      (__attribute__((address_space(3))) void*)l, 16, 0, 0);
}

// ---------------------------------------------------------------------------
// Kernel 0: convert the 5 small fp32 tensors to bf16 in workspace.
// ---------------------------------------------------------------------------
#define N_ED   (512 * 128)        // 65536
#define N_EC   (512 * 128)        // 65536
#define N_WCD  (128 * 256)        // 32768
#define N_WHID (768 * 1536)       // 1179648
#define N_WCDH (768 * 896)        // 688128
#define N_CONV (N_ED + N_EC + N_WCD + N_WHID + N_WCDH)   // 2031616 (= 992*256*8)

__global__ void convert_weights_kernel(const float* __restrict__ Ed,
                                       const float* __restrict__ Ec,
                                       const float* __restrict__ Wcd,
                                       const float* __restrict__ Whid,
                                       const float* __restrict__ Wcdh,
                                       unsigned short* __restrict__ ed_b,
                                       unsigned short* __restrict__ ec_b,
                                       unsigned short* __restrict__ wcd_b,
                                       unsigned short* __restrict__ whid_b,
                                       unsigned short* __restrict__ wcdh_b) {
  long i = ((long)blockIdx.x * blockDim.x + threadIdx.x) * 8;
  const float* s; unsigned short* dst; long off;
  if (i < N_ED)                            { s = Ed;   dst = ed_b;   off = i; }
  else if (i < N_ED + N_EC)                { s = Ec;   dst = ec_b;   off = i - N_ED; }
  else if (i < N_ED + N_EC + N_WCD)        { s = Wcd;  dst = wcd_b;  off = i - (N_ED + N_EC); }
  else if (i < N_ED + N_EC + N_WCD + N_WHID) { s = Whid; dst = whid_b; off = i - (N_ED + N_EC + N_WCD); }
  else                                     { s = Wcdh; dst = wcdh_b; off = i - (N_ED + N_EC + N_WCD + N_WHID); }
  floatx4 v0 = *(const floatx4*)(s + off);
  floatx4 v1 = *(const floatx4*)(s + off + 4);
  ushort8 o;
#pragma unroll
  for (int t = 0; t < 4; ++t) { o[t] = f2bf(v0[t]); o[t + 4] = f2bf(v1[t]); }
  *(ushort8*)(dst + off) = o;
}

// ---------------------------------------------------------------------------
// Kernel 1: seqs_u = seqs + E_u[u]  -> d_out (fp32) and ws bf16 copy
// ---------------------------------------------------------------------------
__global__ void embed_add_kernel(const float* __restrict__ seqs,
                                 const int* __restrict__ u,
                                 const float* __restrict__ Eu,
                                 float* __restrict__ out,
                                 unsigned short* __restrict__ sub, int nchunks) {
  int c = blockIdx.x * blockDim.x + threadIdx.x;
  if (c >= nchunks) return;
  int row = c / 96;            // 96 chunks of 8 per 768-row
  int hc  = c - row * 96;
  int uid = u[row];
  const floatx4* sp = (const floatx4*)seqs + (size_t)c * 2;
  const floatx4* ep = (const floatx4*)(Eu + (size_t)uid * H_DIM + hc * 8);
  floatx4 a0 = sp[0], a1 = sp[1];
  floatx4 b0 = ep[0], b1 = ep[1];
  floatx4 r0, r1; ushort8 ob;
#pragma unroll
  for (int t = 0; t < 4; ++t) {
    r0[t] = a0[t] + b0[t];
    r1[t] = a1[t] + b1[t];
    ob[t] = f2bf(r0[t]); ob[t + 4] = f2bf(r1[t]);
  }
  floatx4* op = (floatx4*)out + (size_t)c * 2;
  op[0] = r0; op[1] = r1;
  *((ushort8*)sub + c) = ob;
}

// ---------------------------------------------------------------------------
// Fused NT GEMM with relu:  out[n, o] = relu(sum_k A[n,k] * W[o,k])  (all bf16)
// MODE 0: A = cat(E_d[d[n]], E_c[c[n]])          K=256,  NOUT=128
// MODE 1: A = pairs(seqs_u)[n] == sub[n..n+1536) K=1536, NOUT=768  (CONTIGUOUS!)
// MODE 2: A = cat(ph[n], d_c[n])                 K=896,  NOUT=768
// 128x128 block tile, 4 waves (2x2), each wave 4x4 MFMA 16x16x32 frags.
//
// Round 3 changes:
//  * Double-buffered LDS (64 KB) + depth-1 prefetch: STAGE(t+1) issued before
//    COMPUTE(t); ONE __syncthreads per iteration. Its implicit vmcnt(0) drain
//    now lands AFTER the MFMA cluster -> load latency overlapped.
//    Race audit: barrier@end(t-1) ensures all waves finished reading
//    buf[(t-1)&1] before any STAGE(t+1) (same buffer) write is issued.
//  * Per-thread staging base pointers hoisted out of the K-loop (MODE1's
//    div-by-2047 + branch ran per load per tile; pairs view is contiguous:
//    A(n,k) = sub[(b*2048+s)*768 + k] for all k in [0,1536)).
//  * T5: s_setprio(1) around each MFMA cluster.
// Kept from round 2 (verified: conflicts=0, FETCH 308->55MB):
//  * T1 bijective XCD-chunked blockIdx remap.
//  * T2 XOR swizzle, both-sides (pre-swizzled global src + swizzled ds_read).
// ---------------------------------------------------------------------------
template <int MODE, int K, int LDW, int NOUT>
__global__ __launch_bounds__(256)
void gemm_nt_relu(const unsigned short* __restrict__ A0,
                  const unsigned short* __restrict__ A1,
                  const int* __restrict__ idx0,
                  const int* __restrict__ idx1,
                  const unsigned short* __restrict__ W,
                  unsigned short* __restrict__ out) {
  constexpr int NT = NOUT / 128;
  constexpr int NTILES = K / 64;

  // --- T1: bijective XCD chunking (m204) ---
  const int nwg = gridDim.x;
  const int q = nwg >> 3, r = nwg & 7;
  const int xcd = blockIdx.x & 7, lid = blockIdx.x >> 3;
  const int wgid = (xcd < r ? xcd * (q + 1) : r * (q + 1) + (xcd - r) * q) + lid;
  const int bm = wgid / NT;
  const int bn = wgid - bm * NT;

  __shared__ unsigned short As[2][128 * 64];
  __shared__ unsigned short Ws[2][128 * 64];

  const int tid  = threadIdx.x;
  const int lane = tid & 63;
  const int wave = tid >> 6;
  const int lrow = lane >> 3;   // 0..7  (== staged LDS row & 7)
  const int cc   = lane & 7;    // 16B chunk slot within 64-col row (LDS side)
  const int scc  = cc ^ lrow;   // pre-swizzled GLOBAL chunk for this slot
  const int wm   = wave >> 1, wn = wave & 1;
  const int m16  = lane & 15, quad = lane >> 4;
  const int rxor = m16 & 7;     // read-side XOR (row & 7)

  // ---- hoisted per-thread staging base pointers (4 staged rows each) ----
  const unsigned short* gA[4];
  const unsigned short* gA2[4];
  const unsigned short* gW[4];
#pragma unroll
  for (int it = 0; it < 4; ++it) {
    int row = it * 32 + wave * 8 + lrow;
    int n = bm * 128 + row;
    if (n >= M_ROWS) n = M_ROWS - 1;   // clamp: read valid, store masked later
    if constexpr (MODE == 0) {
      gA[it]  = A0 + (size_t)idx0[n] * 128 + scc * 8;
      gA2[it] = A1 + (size_t)idx1[n] * 128 + scc * 8;
    } else if constexpr (MODE == 1) {
      int b = n / (S_LEN - 1);
      int s = n - b * (S_LEN - 1);
      // pairs(n) = sub rows (b*2048+s, b*2048+s+1) = contiguous 1536 elements
      gA[it]  = A0 + (size_t)(b * S_LEN + s) * H_DIM + scc * 8;
      gA2[it] = gA[it];   // unused
    } else {
      gA[it]  = A0 + (size_t)n * H_DIM + scc * 8;
      gA2[it] = A1 + (size_t)n * 128 + scc * 8;
    }
    int wrow = bn * 128 + row;
    gW[it] = W + (size_t)wrow * LDW + scc * 8;
  }

  floatx4 acc[4][4] = {};

  // stage one 64-deep K-tile (A + W) into buffer `buf`
  auto STAGE = [&](int kt, int buf) {
    const int colbase = kt * 64;
#pragma unroll
    for (int it = 0; it < 4; ++it) {
      const unsigned short* g;
      if constexpr (MODE == 0) {
        g = (colbase < 128) ? gA[it] + colbase : gA2[it] + (colbase - 128);
      } else if constexpr (MODE == 1) {
        g = gA[it] + colbase;
      } else {
        g = (colbase < H_DIM) ? gA[it] + colbase : gA2[it] + (colbase - H_DIM);
      }
      load_lds16(g, &As[buf][(it * 256 + wave * 64) * 8]);
      load_lds16(gW[it] + colbase, &Ws[buf][(it * 256 + wave * 64) * 8]);
    }
  };

  // prologue
  STAGE(0, 0);
  __syncthreads();

  for (int kt = 0; kt < NTILES; ++kt) {
    const int cur = kt & 1;
    if (kt + 1 < NTILES) STAGE(kt + 1, cur ^ 1);   // prefetch next tile

    const unsigned short* as = As[cur];
    const unsigned short* ws = Ws[cur];
#pragma unroll
    for (int k8 = 0; k8 < 8; k8 += 4) {   // two K=32 slices of the 64-tile
      bf16x8 a[4], b[4];
#pragma unroll
      for (int i = 0; i < 4; ++i) {
        int rr = wm * 64 + i * 16 + m16;
        a[i] = *(const bf16x8*)&as[rr * 64 + (((k8 + quad) ^ rxor) << 3)];
      }
#pragma unroll
      for (int j = 0; j < 4; ++j) {
        int rr = wn * 64 + j * 16 + m16;
        b[j] = *(const bf16x8*)&ws[rr * 64 + (((k8 + quad) ^ rxor) << 3)];
      }
      __builtin_amdgcn_s_setprio(1);
#pragma unroll
      for (int i = 0; i < 4; ++i)
#pragma unroll
        for (int j = 0; j < 4; ++j)
          acc[i][j] = __builtin_amdgcn_mfma_f32_16x16x32_bf16(a[i], b[j], acc[i][j], 0, 0, 0);
      __builtin_amdgcn_s_setprio(0);
    }
    // one barrier per iteration: drains this iteration's prefetch loads
    // (overlapped by the MFMA above) + guarantees buf[cur] reads finished
    // before next iteration's STAGE overwrites it.
    __syncthreads();
  }

  // ---- epilogue: relu + bf16 store. C/D: col=lane&15, row=quad*4+reg ----
#pragma unroll
  for (int i = 0; i < 4; ++i) {
#pragma unroll
    for (int r2 = 0; r2 < 4; ++r2) {
      int row = bm * 128 + wm * 64 + i * 16 + quad * 4 + r2;
      if (row < M_ROWS) {
#pragma unroll
        for (int j = 0; j < 4; ++j) {
          int col = bn * 128 + wn * 64 + j * 16 + m16;
          out[(size_t)row * NOUT + col] = f2bf(fmaxf(acc[i][j][r2], 0.0f));
        }
      }
    }
  }
}

// ---------------------------------------------------------------------------
// Kernel 5: out[b,s] += m[b,s]*(s<S-1) + m[b,s-1]*(s>=2)   (out fp32, m bf16)
// ---------------------------------------------------------------------------
__global__ void final_add_kernel(const unsigned short* __restrict__ mm,
                                 float* __restrict__ out, int nchunks) {
  int c = blockIdx.x * blockDim.x + threadIdx.x;
  if (c >= nchunks) return;
  int row = c / 96;
  int hc  = c - row * 96;
  int b = row >> 11;            // S_LEN = 2048
  int s = row & (S_LEN - 1);
  floatx4* op = (floatx4*)out + (size_t)c * 2;
  floatx4 v0 = op[0], v1 = op[1];
  int mrow = b * (S_LEN - 1) + s;
  if (s < S_LEN - 1) {
    ushort8 x = *(const ushort8*)(mm + (size_t)mrow * H_DIM + hc * 8);
#pragma unroll
    for (int t = 0; t < 4; ++t) { v0[t] += bf2f(x[t]); v1[t] += bf2f(x[t + 4]); }
  }
  if (s >= 2) {
    ushort8 x = *(const ushort8*)(mm + (size_t)(mrow - 1) * H_DIM + hc * 8);
#pragma unroll
    for (int t = 0; t < 4; ++t) { v0[t] += bf2f(x[t]); v1[t] += bf2f(x[t + 4]); }
  }
  op[0] = v0; op[1] = v1;
}

// ---------------------------------------------------------------------------
extern "C" void kernel_launch(void* const* d_in, const int* in_sizes, int n_in,
                              void* d_out, int out_size, void* d_ws, size_t ws_size,
                              hipStream_t stream) {
  const float* seqs  = (const float*)d_in[0];
  const int*   d_idx = (const int*)d_in[1];
  const int*   c_idx = (const int*)d_in[2];
  const int*   u_idx = (const int*)d_in[3];
  const float* E_d   = (const float*)d_in[4];
  const float* E_c   = (const float*)d_in[5];
  const float* E_u   = (const float*)d_in[6];
  const float* W_cd  = (const float*)d_in[7];
  const float* W_hid = (const float*)d_in[8];
  const float* W_cdh = (const float*)d_in[9];
  float* out = (float*)d_out;

  // bf16 workspace layout (ushort units); all segment sizes are multiples of 8
  unsigned short* sub   = (unsigned short*)d_ws;                 // seqs_u bf16 [16*2048, 768]
  unsigned short* ph    = sub   + (size_t)B_SZ * S_LEN * H_DIM;  // [32752, 768]
  unsigned short* mmb   = ph    + (size_t)M_ROWS * H_DIM;        // [32752, 768]
  unsigned short* dc    = mmb   + (size_t)M_ROWS * H_DIM;        // [32752, 128]
  unsigned short* ed_b  = dc    + (size_t)M_ROWS * 128;
  unsigned short* ec_b  = ed_b  + N_ED;
  unsigned short* wcd_b = ec_b  + N_EC;
  unsigned short* whid_b = wcd_b + N_WCD;
  unsigned short* wcdh_b = whid_b + N_WHID;

  const int nchunks = B_SZ * S_LEN * (H_DIM / 8);   // 3,145,728
  const int mtiles = (M_ROWS + 127) / 128;          // 256

  // 0) fp32 -> bf16 conversions of embeddings + weights
  convert_weights_kernel<<<N_CONV / (256 * 8), 256, 0, stream>>>(
      E_d, E_c, W_cd, W_hid, W_cdh, ed_b, ec_b, wcd_b, whid_b, wcdh_b);
  // 1) seqs_u = seqs + E_u[u]  -> out (fp32) + sub (bf16)
  embed_add_kernel<<<(nchunks + 255) / 256, 256, 0, stream>>>(seqs, u_idx, E_u, out, sub, nchunks);
  // 2) d_c = relu(cat(E_d[d], E_c[c]) @ W_cd^T)
  gemm_nt_relu<0, 256, 256, 128><<<mtiles * 1, 256, 0, stream>>>(ed_b, ec_b, d_idx, c_idx, wcd_b, dc);
  // 3) ph = relu(pairs(seqs_u) @ W_hid^T)
  gemm_nt_relu<1, 1536, 1536, 768><<<mtiles * 6, 256, 0, stream>>>(sub, nullptr, nullptr, nullptr, whid_b, ph);
  // 4) m = relu(cat(ph, d_c) @ W_cdh^T)
  gemm_nt_relu<2, 896, 896, 768><<<mtiles * 6, 256, 0, stream>>>(ph, dc, nullptr, nullptr, wcdh_b, mmb);
  // 5) out += shifted m
  final_add_kernel<<<(nchunks + 255) / 256, 256, 0, stream>>>(mmb, out, nchunks);
}

// Round 4
// 546.749 us; speedup vs baseline: 1.0545x; 1.0046x over previous
//
#include <hip/hip_runtime.h>
#include <hip/hip_bf16.h>
#include <cstdint>
#include <cstddef>

// Problem constants
#define B_SZ   16
#define S_LEN  2048
#define H_DIM  768
#define M_ROWS (B_SZ * (S_LEN - 1))   // 32752 GEMM rows

typedef __attribute__((ext_vector_type(8))) __bf16 bf16x8;
typedef __attribute__((ext_vector_type(8))) unsigned short ushort8;
typedef __attribute__((ext_vector_type(4))) float floatx4;

__device__ __forceinline__ float bf2f(unsigned short h) {
  union { unsigned u; float f; } v; v.u = ((unsigned)h) << 16; return v.f;
}
__device__ __forceinline__ unsigned short f2bf(float f) {
  union { float f; unsigned u; } v; v.f = f;
  unsigned u = v.u + 0x7fffu + ((v.u >> 16) & 1u);  // RNE
  return (unsigned short)(u >> 16);
}

// async global->LDS, 16B per lane. LDS dest = wave-uniform base + lane*16.
__device__ __forceinline__ void load_lds16(const void* g, void* l) {
  __builtin_amdgcn_global_load_lds(
      (const __attribute__((address_space(1))) void*)g,
      (__attribute__((address_space(3))) void*)l, 16, 0, 0);
}

// ---------------------------------------------------------------------------
// Kernel 0: convert the 5 small fp32 tensors to bf16 in workspace.
// ---------------------------------------------------------------------------
#define N_ED   (512 * 128)        // 65536
#define N_EC   (512 * 128)        // 65536
#define N_WCD  (128 * 256)        // 32768
#define N_WHID (768 * 1536)       // 1179648
#define N_WCDH (768 * 896)        // 688128
#define N_CONV (N_ED + N_EC + N_WCD + N_WHID + N_WCDH)   // 2031616 (= 992*256*8)

__global__ void convert_weights_kernel(const float* __restrict__ Ed,
                                       const float* __restrict__ Ec,
                                       const float* __restrict__ Wcd,
                                       const float* __restrict__ Whid,
                                       const float* __restrict__ Wcdh,
                                       unsigned short* __restrict__ ed_b,
                                       unsigned short* __restrict__ ec_b,
                                       unsigned short* __restrict__ wcd_b,
                                       unsigned short* __restrict__ whid_b,
                                       unsigned short* __restrict__ wcdh_b) {
  long i = ((long)blockIdx.x * blockDim.x + threadIdx.x) * 8;
  const float* s; unsigned short* dst; long off;
  if (i < N_ED)                            { s = Ed;   dst = ed_b;   off = i; }
  else if (i < N_ED + N_EC)                { s = Ec;   dst = ec_b;   off = i - N_ED; }
  else if (i < N_ED + N_EC + N_WCD)        { s = Wcd;  dst = wcd_b;  off = i - (N_ED + N_EC); }
  else if (i < N_ED + N_EC + N_WCD + N_WHID) { s = Whid; dst = whid_b; off = i - (N_ED + N_EC + N_WCD); }
  else                                     { s = Wcdh; dst = wcdh_b; off = i - (N_ED + N_EC + N_WCD + N_WHID); }
  floatx4 v0 = *(const floatx4*)(s + off);
  floatx4 v1 = *(const floatx4*)(s + off + 4);
  ushort8 o;
#pragma unroll
  for (int t = 0; t < 4; ++t) { o[t] = f2bf(v0[t]); o[t + 4] = f2bf(v1[t]); }
  *(ushort8*)(dst + off) = o;
}

// ---------------------------------------------------------------------------
// Kernel 1: seqs_u = seqs + E_u[u]  -> d_out (fp32) and ws bf16 copy
// ---------------------------------------------------------------------------
__global__ void embed_add_kernel(const float* __restrict__ seqs,
                                 const int* __restrict__ u,
                                 const float* __restrict__ Eu,
                                 float* __restrict__ out,
                                 unsigned short* __restrict__ sub, int nchunks) {
  int c = blockIdx.x * blockDim.x + threadIdx.x;
  if (c >= nchunks) return;
  int row = c / 96;            // 96 chunks of 8 per 768-row
  int hc  = c - row * 96;
  int uid = u[row];
  const floatx4* sp = (const floatx4*)seqs + (size_t)c * 2;
  const floatx4* ep = (const floatx4*)(Eu + (size_t)uid * H_DIM + hc * 8);
  floatx4 a0 = sp[0], a1 = sp[1];
  floatx4 b0 = ep[0], b1 = ep[1];
  floatx4 r0, r1; ushort8 ob;
#pragma unroll
  for (int t = 0; t < 4; ++t) {
    r0[t] = a0[t] + b0[t];
    r1[t] = a1[t] + b1[t];
    ob[t] = f2bf(r0[t]); ob[t + 4] = f2bf(r1[t]);
  }
  floatx4* op = (floatx4*)out + (size_t)c * 2;
  op[0] = r0; op[1] = r1;
  *((ushort8*)sub + c) = ob;
}

// ---------------------------------------------------------------------------
// Fused NT GEMM with relu:  out[n, o] = relu(sum_k A[n,k] * W[o,k])  (all bf16)
// MODE 0: A = cat(E_d[d[n]], E_c[c[n]])          K=256,  NOUT=128
// MODE 1: A = pairs(seqs_u)[n] == sub[n..n+1536) K=1536, NOUT=768  (CONTIGUOUS!)
// MODE 2: A = cat(ph[n], d_c[n])                 K=896,  NOUT=768
// 128x128 block tile, 4 waves (2x2), each wave 4x4 MFMA 16x16x32 frags.
//
// Round 4: T4 counted-vmcnt pipeline (the m218 lever).
//  Round-3's dbuf was neutral because __syncthreads() compiles to a full
//  s_waitcnt vmcnt(0) drain -> prefetch never stayed in flight. Replaced with
//  raw s_barrier + inline-asm s_waitcnt vmcnt(8): tile kt+2's 8 loads remain
//  outstanding across the barrier; we only wait for tile kt+1's 8.
//  Race audit:
//   - barrier #1 (post-compute): every wave's ds_reads of buf[cur] are
//     consumed by MFMAs (compiler lgkmcnt waits) before it arrives ->
//     data latched; only then can any wave's STAGE overwrite buf[cur].
//   - vmcnt(8) after STAGE(kt+2) proves THIS wave's tile-(kt+1) loads done;
//     barrier #2 globalizes that across waves before buf[cur^1] is read.
//   - uniform trip count -> no barrier divergence. No compiler-tracked vmem
//     results live in the loop (global_load_lds has no dest reg) -> hipcc
//     emits no competing vmcnt waits.
// Kept (verified): T1 XCD remap, T2 both-sides XOR swizzle (conflicts=0,
//  FETCH 308->55MB), hoisted base pointers, T5 setprio around MFMA.
// ---------------------------------------------------------------------------
template <int MODE, int K, int LDW, int NOUT>
__global__ __launch_bounds__(256)
void gemm_nt_relu(const unsigned short* __restrict__ A0,
                  const unsigned short* __restrict__ A1,
                  const int* __restrict__ idx0,
                  const int* __restrict__ idx1,
                  const unsigned short* __restrict__ W,
                  unsigned short* __restrict__ out) {
  constexpr int NT = NOUT / 128;
  constexpr int NTILES = K / 64;

  // --- T1: bijective XCD chunking (m204) ---
  const int nwg = gridDim.x;
  const int q = nwg >> 3, r = nwg & 7;
  const int xcd = blockIdx.x & 7, lid = blockIdx.x >> 3;
  const int wgid = (xcd < r ? xcd * (q + 1) : r * (q + 1) + (xcd - r) * q) + lid;
  const int bm = wgid / NT;
  const int bn = wgid - bm * NT;

  __shared__ unsigned short As[2][128 * 64];
  __shared__ unsigned short Ws[2][128 * 64];

  const int tid  = threadIdx.x;
  const int lane = tid & 63;
  const int wave = tid >> 6;
  const int lrow = lane >> 3;   // 0..7  (== staged LDS row & 7)
  const int cc   = lane & 7;    // 16B chunk slot within 64-col row (LDS side)
  const int scc  = cc ^ lrow;   // pre-swizzled GLOBAL chunk for this slot
  const int wm   = wave >> 1, wn = wave & 1;
  const int m16  = lane & 15, quad = lane >> 4;
  const int rxor = m16 & 7;     // read-side XOR (row & 7)

  // ---- hoisted per-thread staging base pointers (4 staged rows each) ----
  const unsigned short* gA[4];
  const unsigned short* gA2[4];
  const unsigned short* gW[4];
#pragma unroll
  for (int it = 0; it < 4; ++it) {
    int row = it * 32 + wave * 8 + lrow;
    int n = bm * 128 + row;
    if (n >= M_ROWS) n = M_ROWS - 1;   // clamp: read valid, store masked later
    if constexpr (MODE == 0) {
      gA[it]  = A0 + (size_t)idx0[n] * 128 + scc * 8;
      gA2[it] = A1 + (size_t)idx1[n] * 128 + scc * 8;
    } else if constexpr (MODE == 1) {
      int b = n / (S_LEN - 1);
      int s = n - b * (S_LEN - 1);
      // pairs(n) = sub rows (b*2048+s, b*2048+s+1) = contiguous 1536 elements
      gA[it]  = A0 + (size_t)(b * S_LEN + s) * H_DIM + scc * 8;
      gA2[it] = gA[it];   // unused
    } else {
      gA[it]  = A0 + (size_t)n * H_DIM + scc * 8;
      gA2[it] = A1 + (size_t)n * 128 + scc * 8;
    }
    int wrow = bn * 128 + row;
    gW[it] = W + (size_t)wrow * LDW + scc * 8;
  }

  floatx4 acc[4][4] = {};

  // stage one 64-deep K-tile (A + W) into buffer `buf`: 8 loads/thread
  auto STAGE = [&](int kt, int buf) {
    const int colbase = kt * 64;
#pragma unroll
    for (int it = 0; it < 4; ++it) {
      const unsigned short* g;
      if constexpr (MODE == 0) {
        g = (colbase < 128) ? gA[it] + colbase : gA2[it] + (colbase - 128);
      } else if constexpr (MODE == 1) {
        g = gA[it] + colbase;
      } else {
        g = (colbase < H_DIM) ? gA[it] + colbase : gA2[it] + (colbase - H_DIM);
      }
      load_lds16(g, &As[buf][(it * 256 + wave * 64) * 8]);
      load_lds16(gW[it] + colbase, &Ws[buf][(it * 256 + wave * 64) * 8]);
    }
  };

  // ---- prologue: 2 tiles in flight, wait for tile 0 only ----
  STAGE(0, 0);
  STAGE(1, 1);
  asm volatile("s_waitcnt vmcnt(8)" ::: "memory");
  __builtin_amdgcn_s_barrier();

  for (int kt = 0; kt < NTILES; ++kt) {
    const int cur = kt & 1;
    const unsigned short* as = As[cur];
    const unsigned short* ws = Ws[cur];
#pragma unroll
    for (int k8 = 0; k8 < 8; k8 += 4) {   // two K=32 slices of the 64-tile
      bf16x8 a[4], b[4];
#pragma unroll
      for (int i = 0; i < 4; ++i) {
        int rr = wm * 64 + i * 16 + m16;
        a[i] = *(const bf16x8*)&as[rr * 64 + (((k8 + quad) ^ rxor) << 3)];
      }
#pragma unroll
      for (int j = 0; j < 4; ++j) {
        int rr = wn * 64 + j * 16 + m16;
        b[j] = *(const bf16x8*)&ws[rr * 64 + (((k8 + quad) ^ rxor) << 3)];
      }
      __builtin_amdgcn_s_setprio(1);
#pragma unroll
      for (int i = 0; i < 4; ++i)
#pragma unroll
        for (int j = 0; j < 4; ++j)
          acc[i][j] = __builtin_amdgcn_mfma_f32_16x16x32_bf16(a[i], b[j], acc[i][j], 0, 0, 0);
      __builtin_amdgcn_s_setprio(0);
    }

    // barrier #1: all waves finished reading buf[cur] (ds_read results were
    // consumed by the MFMAs above -> latched before arrival).
    __builtin_amdgcn_s_barrier();

    if (kt + 2 < NTILES) {
      STAGE(kt + 2, cur);                     // overwrite freed buf[cur]
      // wait for tile kt+1 (8 older loads); kt+2's 8 stay in flight.
      asm volatile("s_waitcnt vmcnt(8)" ::: "memory");
    } else {
      // tail: no more staging; drain what's left (last tile's loads).
      asm volatile("s_waitcnt vmcnt(0)" ::: "memory");
    }
    // barrier #2: globalize per-wave vmcnt guarantee -> buf[cur^1] ready.
    __builtin_amdgcn_s_barrier();
  }

  // ---- epilogue: relu + bf16 store. C/D: col=lane&15, row=quad*4+reg ----
#pragma unroll
  for (int i = 0; i < 4; ++i) {
#pragma unroll
    for (int r2 = 0; r2 < 4; ++r2) {
      int row = bm * 128 + wm * 64 + i * 16 + quad * 4 + r2;
      if (row < M_ROWS) {
#pragma unroll
        for (int j = 0; j < 4; ++j) {
          int col = bn * 128 + wn * 64 + j * 16 + m16;
          out[(size_t)row * NOUT + col] = f2bf(fmaxf(acc[i][j][r2], 0.0f));
        }
      }
    }
  }
}

// ---------------------------------------------------------------------------
// Kernel 5: out[b,s] += m[b,s]*(s<S-1) + m[b,s-1]*(s>=2)   (out fp32, m bf16)
// ---------------------------------------------------------------------------
__global__ void final_add_kernel(const unsigned short* __restrict__ mm,
                                 float* __restrict__ out, int nchunks) {
  int c = blockIdx.x * blockDim.x + threadIdx.x;
  if (c >= nchunks) return;
  int row = c / 96;
  int hc  = c - row * 96;
  int b = row >> 11;            // S_LEN = 2048
  int s = row & (S_LEN - 1);
  floatx4* op = (floatx4*)out + (size_t)c * 2;
  floatx4 v0 = op[0], v1 = op[1];
  int mrow = b * (S_LEN - 1) + s;
  if (s < S_LEN - 1) {
    ushort8 x = *(const ushort8*)(mm + (size_t)mrow * H_DIM + hc * 8);
#pragma unroll
    for (int t = 0; t < 4; ++t) { v0[t] += bf2f(x[t]); v1[t] += bf2f(x[t + 4]); }
  }
  if (s >= 2) {
    ushort8 x = *(const ushort8*)(mm + (size_t)(mrow - 1) * H_DIM + hc * 8);
#pragma unroll
    for (int t = 0; t < 4; ++t) { v0[t] += bf2f(x[t]); v1[t] += bf2f(x[t + 4]); }
  }
  op[0] = v0; op[1] = v1;
}

// ---------------------------------------------------------------------------
extern "C" void kernel_launch(void* const* d_in, const int* in_sizes, int n_in,
                              void* d_out, int out_size, void* d_ws, size_t ws_size,
                              hipStream_t stream) {
  const float* seqs  = (const float*)d_in[0];
  const int*   d_idx = (const int*)d_in[1];
  const int*   c_idx = (const int*)d_in[2];
  const int*   u_idx = (const int*)d_in[3];
  const float* E_d   = (const float*)d_in[4];
  const float* E_c   = (const float*)d_in[5];
  const float* E_u   = (const float*)d_in[6];
  const float* W_cd  = (const float*)d_in[7];
  const float* W_hid = (const float*)d_in[8];
  const float* W_cdh = (const float*)d_in[9];
  float* out = (float*)d_out;

  // bf16 workspace layout (ushort units); all segment sizes are multiples of 8
  unsigned short* sub   = (unsigned short*)d_ws;                 // seqs_u bf16 [16*2048, 768]
  unsigned short* ph    = sub   + (size_t)B_SZ * S_LEN * H_DIM;  // [32752, 768]
  unsigned short* mmb   = ph    + (size_t)M_ROWS * H_DIM;        // [32752, 768]
  unsigned short* dc    = mmb   + (size_t)M_ROWS * H_DIM;        // [32752, 128]
  unsigned short* ed_b  = dc    + (size_t)M_ROWS * 128;
  unsigned short* ec_b  = ed_b  + N_ED;
  unsigned short* wcd_b = ec_b  + N_EC;
  unsigned short* whid_b = wcd_b + N_WCD;
  unsigned short* wcdh_b = whid_b + N_WHID;

  const int nchunks = B_SZ * S_LEN * (H_DIM / 8);   // 3,145,728
  const int mtiles = (M_ROWS + 127) / 128;          // 256

  // 0) fp32 -> bf16 conversions of embeddings + weights
  convert_weights_kernel<<<N_CONV / (256 * 8), 256, 0, stream>>>(
      E_d, E_c, W_cd, W_hid, W_cdh, ed_b, ec_b, wcd_b, whid_b, wcdh_b);
  // 1) seqs_u = seqs + E_u[u]  -> out (fp32) + sub (bf16)
  embed_add_kernel<<<(nchunks + 255) / 256, 256, 0, stream>>>(seqs, u_idx, E_u, out, sub, nchunks);
  // 2) d_c = relu(cat(E_d[d], E_c[c]) @ W_cd^T)
  gemm_nt_relu<0, 256, 256, 128><<<mtiles * 1, 256, 0, stream>>>(ed_b, ec_b, d_idx, c_idx, wcd_b, dc);
  // 3) ph = relu(pairs(seqs_u) @ W_hid^T)
  gemm_nt_relu<1, 1536, 1536, 768><<<mtiles * 6, 256, 0, stream>>>(sub, nullptr, nullptr, nullptr, whid_b, ph);
  // 4) m = relu(cat(ph, d_c) @ W_cdh^T)
  gemm_nt_relu<2, 896, 896, 768><<<mtiles * 6, 256, 0, stream>>>(ph, dc, nullptr, nullptr, wcdh_b, mmb);
  // 5) out += shifted m
  final_add_kernel<<<(nchunks + 255) / 256, 256, 0, stream>>>(mmb, out, nchunks);
}